// Round 8
// baseline (411.235 us; speedup 1.0000x reference)
//
#include <hip/hip_runtime.h>
#include <hip/hip_bf16.h>

// B=2, S=2048, D=2048, H=16, HD=128, causal MHA with 4 linear projections.
// one cvt launch (uniform grid, 3 activations + 4 weights) -> batched QKV GEMM
// (ks-split 2-phase, hoisted frag reads, counted vmcnt, XCD-clustered blocks,
// V transposed per head) -> flash attn (8-wave blocks sharing K/V tiles:
// 128 q-rows per iteration, uniform 34-iter pairing, transposed scores,
// per-lane softmax rows, lane-partial l_i, dbuf K/V, XCD-grouped heads) ->
// out-proj GEMM (same schedule).

#define LOG2E 1.44269504088896340736f

typedef __attribute__((ext_vector_type(8))) short short8;    // 8 x bf16
typedef __attribute__((ext_vector_type(4))) short short4b;   // 4 x bf16
typedef __attribute__((ext_vector_type(4))) float floatx4;   // MFMA acc

__device__ __forceinline__ short f2bf(float f) {
  unsigned int u = __builtin_bit_cast(unsigned int, f);
  u += 0x7FFFu + ((u >> 16) & 1u);  // RNE
  return (short)(u >> 16);
}

__device__ __forceinline__ short8 cvt8(float4 f0, float4 f1) {
  return (short8){f2bf(f0.x), f2bf(f0.y), f2bf(f0.z), f2bf(f0.w),
                  f2bf(f1.x), f2bf(f1.y), f2bf(f1.z), f2bf(f1.w)};
}

__device__ __forceinline__ short4b pack4bf(float a, float b, float c, float d) {
  __hip_bfloat162 lo = __float22bfloat162_rn(float2{a, b});
  __hip_bfloat162 hi = __float22bfloat162_rn(float2{c, d});
  short4b r;
  r[0] = __builtin_bit_cast(short, lo.x); r[1] = __builtin_bit_cast(short, lo.y);
  r[2] = __builtin_bit_cast(short, hi.x); r[3] = __builtin_bit_cast(short, hi.y);
  return r;
}

__device__ __forceinline__ void gl_lds16(const void* g, void* l) {
  __builtin_amdgcn_global_load_lds(
      (const __attribute__((address_space(1))) unsigned int*)g,
      (__attribute__((address_space(3))) unsigned int*)l, 16, 0, 0);
}

// ---------------- fp32 -> bf16 conversion, 7 tensors, uniform grid ----------
__global__ __launch_bounds__(256) void cvt7_k(
    const float* __restrict__ s0, const float* __restrict__ s1,
    const float* __restrict__ s2, const float* __restrict__ s3,
    const float* __restrict__ s4, const float* __restrict__ s5,
    const float* __restrict__ s6,
    unsigned short* __restrict__ d0, unsigned short* __restrict__ d1,
    unsigned short* __restrict__ d2, unsigned short* __restrict__ d3,
    unsigned short* __restrict__ d4, unsigned short* __restrict__ d5,
    unsigned short* __restrict__ d6, int nAct, int nW)
{
  const float* s; unsigned short* d; int n;
  switch (blockIdx.y) {
    case 0: s = s0; d = d0; n = nAct; break;
    case 1: s = s1; d = d1; n = nAct; break;
    case 2: s = s2; d = d2; n = nAct; break;
    case 3: s = s3; d = d3; n = nW; break;
    case 4: s = s4; d = d4; n = nW; break;
    case 5: s = s5; d = d5; n = nW; break;
    default: s = s6; d = d6; n = nW; break;
  }
  const long i = ((long)blockIdx.x * 256 + threadIdx.x) * 8;
  if (i >= n) return;
  float4 a = *(const float4*)(s + i);
  float4 b = *(const float4*)(s + i + 4);
  *(short8*)(d + i) = cvt8(a, b);
}

// ============ shared GEMM body (ks-split 2-phase, hoisted reads) =============
#define GEMM_CORE(A_, Bt_)                                                     \
  const unsigned short* gA[4]; int lAo[4];                                     \
  const unsigned short* gB[2]; int lBo[2];                                     \
  _Pragma("unroll")                                                            \
  for (int j = 0; j < 4; ++j) {                                                \
    const int pa = ((j >> 1) * 16 + wave * 2 + (j & 1)) * 64 + lane;           \
    const int r = pa >> 3, cp = pa & 7, cs = cp ^ (r & 7);                     \
    gA[j]  = A_ + (bm + r) * (long)K + cs * 8;                                 \
    lAo[j] = pa * 8;                                                           \
  }                                                                            \
  _Pragma("unroll")                                                            \
  for (int j = 0; j < 2; ++j) {                                                \
    const int pb = (wave * 2 + j) * 64 + lane;                                 \
    const int r = pb >> 3, cp = pb & 7, cs = cp ^ (r & 7);                     \
    gB[j]  = Bt_ + (bn + r) * (long)K + cs * 8;                                \
    lBo[j] = pb * 8;                                                           \
  }                                                                            \
  floatx4 acc[4][4];                                                           \
  _Pragma("unroll")                                                            \
  for (int i = 0; i < 4; ++i)                                                  \
    _Pragma("unroll")                                                          \
    for (int j = 0; j < 4; ++j) acc[i][j] = (floatx4){0.f, 0.f, 0.f, 0.f};     \
  const int NT = K >> 6;                                                       \
  _Pragma("unroll")                                                            \
  for (int j = 0; j < 4; ++j) gl_lds16(gA[j], &As[0][lAo[j]]);                 \
  _Pragma("unroll")                                                            \
  for (int j = 0; j < 2; ++j) gl_lds16(gB[j], &Bs[0][lBo[j]]);                 \
  if (NT > 1) {                                                                \
    _Pragma("unroll")                                                          \
    for (int j = 0; j < 4; ++j) gl_lds16(gA[j] + 64, &As[1][lAo[j]]);          \
    _Pragma("unroll")                                                          \
    for (int j = 0; j < 2; ++j) gl_lds16(gB[j] + 64, &Bs[1][lBo[j]]);          \
    asm volatile("s_waitcnt vmcnt(6)" ::: "memory");                           \
  } else {                                                                     \
    asm volatile("s_waitcnt vmcnt(0)" ::: "memory");                           \
  }                                                                            \
  __builtin_amdgcn_s_barrier();                                                \
  int cur3 = 0;                                                                \
  for (int t = 0; t < NT; ++t) {                                               \
    int nx2 = cur3 + 2; if (nx2 >= 3) nx2 -= 3;                                \
    const long kk2 = (long)(t + 2) * 64;                                       \
    const bool st2 = (t + 2) < NT;                                             \
    const bool st1 = (t + 1) < NT;                                             \
    const unsigned short* Ab = As[cur3];                                       \
    const unsigned short* Bb = Bs[cur3];                                       \
    short8 af0[4], bf0[4], af1[4], bf1[4];                                     \
    _Pragma("unroll")                                                          \
    for (int mt = 0; mt < 4; ++mt)                                             \
      af0[mt] = *(const short8*)&Ab[(wm * 64 + mt * 16 + l16) * 64 +           \
                                    ((quad ^ lx7) * 8)];                       \
    _Pragma("unroll")                                                          \
    for (int nt = 0; nt < 4; ++nt)                                             \
      bf0[nt] = *(const short8*)&Bb[(wn * 64 + nt * 16 + l16) * 64 +           \
                                    ((quad ^ lx7) * 8)];                       \
    _Pragma("unroll")                                                          \
    for (int mt = 0; mt < 4; ++mt)                                             \
      af1[mt] = *(const short8*)&Ab[(wm * 64 + mt * 16 + l16) * 64 +           \
                                    (((4 + quad) ^ lx7) * 8)];                 \
    _Pragma("unroll")                                                          \
    for (int nt = 0; nt < 4; ++nt)                                             \
      bf1[nt] = *(const short8*)&Bb[(wn * 64 + nt * 16 + l16) * 64 +           \
                                    (((4 + quad) ^ lx7) * 8)];                 \
    if (st2) { gl_lds16(gA[0] + kk2, &As[nx2][lAo[0]]);                        \
               gl_lds16(gA[1] + kk2, &As[nx2][lAo[1]]);                        \
               gl_lds16(gA[2] + kk2, &As[nx2][lAo[2]]); }                      \
    __builtin_amdgcn_s_barrier();                                              \
    __builtin_amdgcn_s_setprio(1);                                             \
    _Pragma("unroll")                                                          \
    for (int nt = 0; nt < 4; ++nt)                                             \
      _Pragma("unroll")                                                        \
      for (int mt = 0; mt < 4; ++mt)                                           \
        acc[mt][nt] = __builtin_amdgcn_mfma_f32_16x16x32_bf16(                 \
            af0[mt], bf0[nt], acc[mt][nt], 0, 0, 0);                           \
    __builtin_amdgcn_s_setprio(0);                                             \
    __builtin_amdgcn_s_barrier();                                              \
    if (st2) { gl_lds16(gA[3] + kk2, &As[nx2][lAo[3]]);                        \
               gl_lds16(gB[0] + kk2, &Bs[nx2][lBo[0]]);                        \
               gl_lds16(gB[1] + kk2, &Bs[nx2][lBo[1]]); }                      \
    __builtin_amdgcn_s_setprio(1);                                             \
    _Pragma("unroll")                                                          \
    for (int nt = 0; nt < 4; ++nt)                                             \
      _Pragma("unroll")                                                        \
      for (int mt = 0; mt < 4; ++mt)                                           \
        acc[mt][nt] = __builtin_amdgcn_mfma_f32_16x16x32_bf16(                 \
            af1[mt], bf1[nt], acc[mt][nt], 0, 0, 0);                           \
    __builtin_amdgcn_s_setprio(0);                                             \
    if (st1) {                                                                 \
      if (st2) asm volatile("s_waitcnt vmcnt(6)" ::: "memory");                \
      else     asm volatile("s_waitcnt vmcnt(0)" ::: "memory");                \
    }                                                                          \
    __builtin_amdgcn_s_barrier();                                              \
    cur3 = cur3 + 1 >= 3 ? 0 : cur3 + 1;                                       \
  }

// ---------------- batched QKV GEMM (z = 0:Q, 1:K, 2:V-transposed) -----------
__global__ __launch_bounds__(512, 1) void gemmqkv_k(
    const unsigned short* __restrict__ Aq, const unsigned short* __restrict__ Ak,
    const unsigned short* __restrict__ Av,
    const unsigned short* __restrict__ Bq, const unsigned short* __restrict__ Bk,
    const unsigned short* __restrict__ Bv,
    const float* __restrict__ biq, const float* __restrict__ bik,
    const float* __restrict__ biv,
    unsigned short* __restrict__ Cq, unsigned short* __restrict__ Ck,
    unsigned short* __restrict__ Cv, float qalpha)
{
  constexpr int K = 2048, N = 2048;
  __shared__ __align__(16) unsigned short As[3][256 * 64];
  __shared__ __align__(16) unsigned short Bs[3][128 * 64];

  const int tid  = threadIdx.x;
  const int lane = tid & 63;
  const int wave = tid >> 6;
  const int quad = lane >> 4;
  const int l16  = lane & 15;
  const int lx7  = l16 & 7;
  const int wm   = wave >> 1, wn = wave & 1;

  const unsigned short* A; const unsigned short* Bt; const float* bias;
  unsigned short* C; float alpha = 1.0f; bool vt = false;
  if (blockIdx.z == 0)      { A = Aq; Bt = Bq; bias = biq; C = Cq; alpha = qalpha; }
  else if (blockIdx.z == 1) { A = Ak; Bt = Bk; bias = bik; C = Ck; }
  else                      { A = Av; Bt = Bv; bias = biv; C = Cv; vt = true; }

  // XCD-cluster swizzle (bijective on 16x16): XCD = lin%8 gets 8x4 rectangle.
  const int lin  = (int)(blockIdx.y * 16 + blockIdx.x);
  const int xcd  = lin & 7;
  const int slot = lin >> 3;
  const int bx = (xcd & 1) * 8 + (slot & 7);
  const int by = (xcd >> 1) * 4 + (slot >> 3);
  const long bm = (long)by * 256;
  const long bn = (long)bx * 128;

  GEMM_CORE(A, Bt)

  if (vt) {
    __syncthreads();
    unsigned short* Ct = &As[0][0];  // [128 col][264] transpose staging
#pragma unroll
    for (int nt = 0; nt < 4; ++nt) {
      const int col_l = wn * 64 + nt * 16 + l16;
      const float bval = bias[bn + col_l];
#pragma unroll
      for (int mt = 0; mt < 4; ++mt) {
        const int row_l = wm * 64 + mt * 16 + quad * 4;
#pragma unroll
        for (int rg = 0; rg < 4; ++rg)
          Ct[col_l * 264 + row_l + rg] = (unsigned short)f2bf((acc[mt][nt][rg] + bval) * alpha);
      }
    }
    __syncthreads();
    const int b  = (int)(bm >> 11);
    const int s0 = (int)(bm & 2047);
    const int d   = tid >> 2;   // 0..127
    const int seg = tid & 3;
    unsigned short* dst = C +
        ((long)(b * 16 + bx) * 128 + d) * 2048 + s0 + seg * 64;
    const unsigned short* src = &Ct[d * 264 + seg * 64];
#pragma unroll
    for (int c = 0; c < 8; ++c)
      *(uint4*)(dst + c * 8) = *(const uint4*)(src + c * 8);
  } else {
#pragma unroll
    for (int nt = 0; nt < 4; ++nt) {
      const long col = bn + wn * 64 + nt * 16 + l16;
      const float bval = bias[col];
#pragma unroll
      for (int mt = 0; mt < 4; ++mt) {
#pragma unroll
        for (int rg = 0; rg < 4; ++rg) {
          const long row = bm + wm * 64 + mt * 16 + quad * 4 + rg;
          C[row * (long)N + col] = (unsigned short)f2bf((acc[mt][nt][rg] + bval) * alpha);
        }
      }
    }
  }
}

// ---------------- single GEMM (out-proj): bf16 A -> fp32 out ----------------
__global__ __launch_bounds__(512, 1) void gemmo_k(
    const unsigned short* __restrict__ A, const unsigned short* __restrict__ Bt,
    const float* __restrict__ bias, float* __restrict__ C)
{
  constexpr int K = 2048, N = 2048;
  __shared__ __align__(16) unsigned short As[3][256 * 64];
  __shared__ __align__(16) unsigned short Bs[3][128 * 64];

  const int tid  = threadIdx.x;
  const int lane = tid & 63;
  const int wave = tid >> 6;
  const int quad = lane >> 4;
  const int l16  = lane & 15;
  const int lx7  = l16 & 7;
  const int wm   = wave >> 1, wn = wave & 1;

  const int lin  = (int)(blockIdx.y * 16 + blockIdx.x);
  const int xcd  = lin & 7;
  const int slot = lin >> 3;
  const int bx = (xcd & 1) * 8 + (slot & 7);
  const int by = (xcd >> 1) * 4 + (slot >> 3);
  const long bm = (long)by * 256;
  const long bn = (long)bx * 128;

  GEMM_CORE(A, Bt)

#pragma unroll
  for (int nt = 0; nt < 4; ++nt) {
    const long col = bn + wn * 64 + nt * 16 + l16;
    const float bval = bias[col];
#pragma unroll
    for (int mt = 0; mt < 4; ++mt) {
#pragma unroll
      for (int rg = 0; rg < 4; ++rg) {
        const long row = bm + wm * 64 + mt * 16 + quad * 4 + rg;
        C[row * (long)N + col] = (acc[mt][nt][rg] + bval);
      }
    }
  }
}

// ---------------- fallback GEMM (fp32 operands) -----------------------------
template<bool A_BF16, bool OUT_BF16, bool VT_OUT>
__global__ __launch_bounds__(256, 2) void gemm_bias_k(
    const void* __restrict__ Aptr, const float* __restrict__ Bt,
    const float* __restrict__ bias, void* __restrict__ Cptr,
    int M, int N, int K, float alpha)
{
  __shared__ __align__(16) unsigned short smem[128 * 136];
  unsigned short* As = smem;
  unsigned short* Bs = smem + 128 * 40;

  const int tid  = threadIdx.x;
  const int lane = tid & 63;
  const int wave = tid >> 6;
  const int quad = lane >> 4;
  const int l16  = lane & 15;
  const int wr   = wave >> 1, wc = wave & 1;
  const long bm  = (long)blockIdx.y * 128;
  const long bn  = (long)blockIdx.x * 128;

  floatx4 acc[4][4];
#pragma unroll
  for (int i = 0; i < 4; ++i)
#pragma unroll
    for (int j = 0; j < 4; ++j) acc[i][j] = (floatx4){0.f, 0.f, 0.f, 0.f};

  const int srow = tid >> 2;
  const int cc   = tid & 3;

  for (int k0 = 0; k0 < K; k0 += 32) {
    __syncthreads();
#pragma unroll
    for (int r = 0; r < 2; ++r) {
      const int row = srow + r * 64;
      short8 av, bv;
      if (A_BF16) {
        av = *(const short8*)((const unsigned short*)Aptr + (bm + row) * (long)K + k0 + cc * 8);
      } else {
        const float* ap = (const float*)Aptr + (bm + row) * (long)K + k0 + cc * 8;
        av = cvt8(*(const float4*)ap, *(const float4*)(ap + 4));
      }
      {
        const float* bp = Bt + (bn + row) * (long)K + k0 + cc * 8;
        bv = cvt8(*(const float4*)bp, *(const float4*)(bp + 4));
      }
      *(short8*)&As[row * 40 + cc * 8] = av;
      *(short8*)&Bs[row * 40 + cc * 8] = bv;
    }
    __syncthreads();

    short8 af[4], bf[4];
#pragma unroll
    for (int t = 0; t < 4; ++t) {
      af[t] = *(const short8*)&As[(wr * 64 + t * 16 + l16) * 40 + quad * 8];
      bf[t] = *(const short8*)&Bs[(wc * 64 + t * 16 + l16) * 40 + quad * 8];
    }
#pragma unroll
    for (int mt = 0; mt < 4; ++mt)
#pragma unroll
      for (int nt = 0; nt < 4; ++nt)
        acc[mt][nt] = __builtin_amdgcn_mfma_f32_16x16x32_bf16(af[mt], bf[nt], acc[mt][nt], 0, 0, 0);
  }

  if (VT_OUT) {
    __syncthreads();
    unsigned short* Ct = smem;
#pragma unroll
    for (int nt = 0; nt < 4; ++nt) {
      const long col = bn + wc * 64 + nt * 16 + l16;
      const float bval = bias[col];
      const int col_l = wc * 64 + nt * 16 + l16;
#pragma unroll
      for (int mt = 0; mt < 4; ++mt) {
        const int row_l = wr * 64 + mt * 16 + quad * 4;
#pragma unroll
        for (int rg = 0; rg < 4; ++rg)
          Ct[col_l * 136 + row_l + rg] = (unsigned short)f2bf((acc[mt][nt][rg] + bval) * alpha);
      }
    }
    __syncthreads();
    const int b  = (int)(bm >> 11);
    const int s0 = (int)(bm & 2047);
    const int r    = tid >> 1;
    const int half = tid & 1;
    unsigned short* dst = (unsigned short*)Cptr +
        ((long)(b * 16 + blockIdx.x) * 128 + r) * 2048 + s0 + half * 64;
    const unsigned short* src = &Ct[r * 136 + half * 64];
#pragma unroll
    for (int c = 0; c < 8; ++c)
      *(uint4*)(dst + c * 8) = *(const uint4*)(src + c * 8);
  } else {
#pragma unroll
    for (int nt = 0; nt < 4; ++nt) {
      const long col = bn + wc * 64 + nt * 16 + l16;
      const float bval = bias[col];
#pragma unroll
      for (int mt = 0; mt < 4; ++mt) {
#pragma unroll
        for (int rg = 0; rg < 4; ++rg) {
          const long row = bm + wr * 64 + mt * 16 + quad * 4 + rg;
          const float v = (acc[mt][nt][rg] + bval) * alpha;
          if (OUT_BF16) ((unsigned short*)Cptr)[row * (long)N + col] = (unsigned short)f2bf(v);
          else          ((float*)Cptr)[row * (long)N + col] = v;
        }
      }
    }
  }
}

// ---------------- flash attention: 8-wave shared-K/V blocks -----------------
// Q,K,O: bf16 [B,S,H,HD] (Q pre-scaled by SCALE*LOG2E). Vt: bf16 [B*H][HD][S].
// Block 512 thr = 8 waves; one block covers a 128-row q-pair (q-tiles 2j,2j+1)
// with ALL waves sharing the staged K/V tile -> per-iteration overhead (stage,
// vmcnt, 2 barriers, softmax chain) amortized over 2x rows. Block processes
// pairs {jsel, 15-jsel} sequentially -> uniform 34 iterations. Grid (8,32) =
// 256 blocks = 1/CU (LDS 82KB); bx = XCD owns heads 4bx..4bx+3 (4MB = L2).
// K/V dbuf + counted vmcnt(4). Wave-uniform diag test; sub-tile-0 waves see
// one fully-masked tile per pair (P=0 exactly -> bitwise-identical output).
__global__ __launch_bounds__(512, 1) void flash_attn_k(
    const unsigned short* __restrict__ Q,
    const unsigned short* __restrict__ Kp,
    const unsigned short* __restrict__ Vt,
    unsigned short* __restrict__ O)
{
  constexpr int S = 2048, D = 2048, HD = 128;
  constexpr int PS = 72;  // Ps stride (shorts)

  __shared__ __align__(16) unsigned short Ks[2][64 * 128];   // [k][d], swizzled
  __shared__ __align__(16) unsigned short Vst[2][128 * 64];  // [d][k], swizzled
  __shared__ __align__(16) unsigned short Ps[128 * PS];      // [q_local][k]

  const int tid  = threadIdx.x;
  const int lane = tid & 63;
  const int w    = tid >> 6;      // 0..7
  const int quad = lane >> 4;
  const int l16  = lane & 15;
  const int lx7  = l16 & 7;

  // bx = XCD (grid (8,32): lin%8 = bx); owns heads 4bx..4bx+3.
  const int bx   = blockIdx.x;    // 0..7
  const int by   = blockIdx.y;    // 0..31
  const int bh   = bx * 4 + (by >> 3);
  const int jsel = by & 7;

  const long headoff = (long)(bh >> 4) * S * D + (long)(bh & 15) * HD;
  const long vtoff   = (long)bh * HD * S;

  // staging plan: 512 thr x 2 chunks each for K (64x128) and V (128x64)
  const unsigned short* gK[2]; int oK[2];
  const unsigned short* gV[2]; int oV[2];
#pragma unroll
  for (int i = 0; i < 2; ++i) {
    const int p = (w * 2 + i) * 64 + lane;          // 0..1023
    { const int r = p >> 4, cp = p & 15, c = cp ^ (r & 7);
      gK[i] = Kp + headoff + (long)r * D + c * 8;  oK[i] = p * 8; }
    { const int r = p >> 3, cp = p & 7, c = cp ^ (r & 7);
      gV[i] = Vt + vtoff + (long)r * S + c * 8;    oV[i] = p * 8; }
  }

#pragma unroll 1
  for (int half = 0; half < 2; ++half) {
    const int j     = half ? (15 - jsel) : jsel;
    const int qbase = j * 128;
    const int ktmax = 2 * j + 1;
    const int qrow  = qbase + w * 16 + l16;   // this lane's q row
    const int qloc  = w * 16 + l16;
    const int wrow0 = qbase + w * 16;         // wave's lowest q row

    // Q fragments (B-operand layout: n = l16 = own row, k-chunks of 32)
    short8 aq[4];
    {
      const unsigned short* qp = Q + headoff + (long)qrow * D;
#pragma unroll
      for (int ks = 0; ks < 4; ++ks)
        aq[ks] = *(const short8*)(qp + ks * 32 + quad * 8);
    }

    floatx4 o_acc[8];
#pragma unroll
    for (int t = 0; t < 8; ++t) o_acc[t] = (floatx4){0.f, 0.f, 0.f, 0.f};
    float m_i = -INFINITY;   // row-uniform (updates use row-reduced max)
    float l_p = 0.f;         // per-lane partial of l_i

    // prologue: stage tile 0 into buf 0 (safe: prior half's trailing barrier)
#pragma unroll
    for (int i = 0; i < 2; ++i) gl_lds16(gK[i], &Ks[0][oK[i]]);
#pragma unroll
    for (int i = 0; i < 2; ++i) gl_lds16(gV[i], &Vst[0][oV[i]]);

    for (int kt = 0; kt <= ktmax; ++kt) {
      const int cur = kt & 1;
      const int kbase = kt * 64;
      if (kt < ktmax) {
        const long kb = (long)(kt + 1) * 64;
        const int nb = cur ^ 1;
#pragma unroll
        for (int i = 0; i < 2; ++i) gl_lds16(gK[i] + kb * D, &Ks[nb][oK[i]]);
#pragma unroll
        for (int i = 0; i < 2; ++i) gl_lds16(gV[i] + kb, &Vst[nb][oV[i]]);
        asm volatile("s_waitcnt vmcnt(4)" ::: "memory");  // tile kt landed
      } else {
        asm volatile("s_waitcnt vmcnt(0)" ::: "memory");
      }
      __builtin_amdgcn_s_barrier();   // B1: tile kt visible to all waves

      const unsigned short* Kb = &Ks[cur][0];
      const unsigned short* Vb = &Vst[cur][0];

      // S^T tile: sc[nt] D-layout: k_local = nt*16 + quad*4 + rg, q-col = l16
      floatx4 sc[4];
#pragma unroll
      for (int nt = 0; nt < 4; ++nt) sc[nt] = (floatx4){0.f, 0.f, 0.f, 0.f};
      __builtin_amdgcn_s_setprio(1);
#pragma unroll
      for (int nt = 0; nt < 4; ++nt) {
        const int krow = nt * 16 + l16;
#pragma unroll
        for (int ks = 0; ks < 4; ++ks) {
          const int cp = (ks * 4 + quad) ^ lx7;
          short8 kf = *(const short8*)&Kb[krow * 128 + cp * 8];
          sc[nt] = __builtin_amdgcn_mfma_f32_16x16x32_bf16(kf, aq[ks], sc[nt], 0, 0, 0);
        }
      }
      __builtin_amdgcn_s_setprio(0);

      float sv[4][4];
      float lmax = -INFINITY;   // lane-local max over its 16 k-values
      if (kbase + 63 > wrow0) {  // wave-uniform: some element may need masking
        const int kg0 = kbase + quad * 4;
#pragma unroll
        for (int nt = 0; nt < 4; ++nt)
#pragma unroll
          for (int rg = 0; rg < 4; ++rg) {
            float v = sc[nt][rg];
            if (kg0 + nt * 16 + rg > qrow) v = -INFINITY;
            sv[nt][rg] = v;
            lmax = fmaxf(lmax, v);
          }
      } else {
#pragma unroll
        for (int nt = 0; nt < 4; ++nt)
#pragma unroll
          for (int rg = 0; rg < 4; ++rg) {
            sv[nt][rg] = sc[nt][rg];
            lmax = fmaxf(lmax, sc[nt][rg]);
          }
      }

      // defer-max: lane-local check == row check (m_i row-uniform). Shuffles
      // only on the rare rescale path.
      float al = 1.0f;
      if (__any(lmax > m_i + 8.0f)) {
        float rmax = fmaxf(lmax, __shfl_xor(lmax, 16));
        rmax = fmaxf(rmax, __shfl_xor(rmax, 32));
        const float mn = fmaxf(m_i, rmax);
        al = exp2f(m_i - mn);
        m_i = mn;
#pragma unroll
        for (int t = 0; t < 8; ++t)
#pragma unroll
          for (int rg = 0; rg < 4; ++rg) o_acc[t][rg] *= al;
      }

      float rsum = 0.f;
#pragma unroll
      for (int nt = 0; nt < 4; ++nt) {
        float p0 = exp2f(sv[nt][0] - m_i), p1 = exp2f(sv[nt][1] - m_i);
        float p2 = exp2f(sv[nt][2] - m_i), p3 = exp2f(sv[nt][3] - m_i);
        rsum += (p0 + p1) + (p2 + p3);
        *(short4b*)&Ps[qloc * PS + nt * 16 + quad * 4] = pack4bf(p0, p1, p2, p3);
      }
      l_p = l_p * al + rsum;   // lane-partial; al row-uniform -> sums correctly

      // P fragments (wave-private region of Ps: same-wave write->read, in-order DS)
      short8 pf[2];
#pragma unroll
      for (int ks = 0; ks < 2; ++ks)
        pf[ks] = *(const short8*)&Ps[qloc * PS + ks * 32 + quad * 8];

      // O^T += Vt_tile . P^T
      __builtin_amdgcn_s_setprio(1);
#pragma unroll
      for (int t = 0; t < 8; ++t) {
        const int drow = t * 16 + l16;
#pragma unroll
        for (int ks = 0; ks < 2; ++ks) {
          const int cp = (ks * 4 + quad) ^ lx7;
          short8 vf = *(const short8*)&Vb[drow * 64 + cp * 8];
          o_acc[t] = __builtin_amdgcn_mfma_f32_16x16x32_bf16(vf, pf[ks], o_acc[t], 0, 0, 0);
        }
      }
      __builtin_amdgcn_s_setprio(0);
      __builtin_amdgcn_s_barrier();   // B2: all waves done reading buf cur
    }

    // epilogue: reduce lane-partial l, then lane holds O[qrow][d=t*16+quad*4+rg]
    float l_i = l_p + __shfl_xor(l_p, 16);
    l_i += __shfl_xor(l_i, 32);
    const float rl = 1.0f / l_i;
    unsigned short* op = O + headoff + (long)qrow * D;
#pragma unroll
    for (int t = 0; t < 8; ++t) {
      *(short4b*)(op + t * 16 + quad * 4) =
          pack4bf(o_acc[t][0] * rl, o_acc[t][1] * rl, o_acc[t][2] * rl, o_acc[t][3] * rl);
    }
  }
}

extern "C" void kernel_launch(void* const* d_in, const int* in_sizes, int n_in,
                              void* d_out, int out_size, void* d_ws, size_t ws_size,
                              hipStream_t stream) {
  const float* query = (const float*)d_in[0];
  const float* key_  = (const float*)d_in[1];
  const float* value = (const float*)d_in[2];
  const float* Wq = (const float*)d_in[3];
  const float* bq = (const float*)d_in[4];
  const float* Wk = (const float*)d_in[5];
  const float* bk = (const float*)d_in[6];
  const float* Wv = (const float*)d_in[7];
  const float* bv = (const float*)d_in[8];
  const float* Wo = (const float*)d_in[9];
  const float* bo = (const float*)d_in[10];
  float* out = (float*)d_out;

  constexpr int Bz = 2, S = 2048, D = 2048;
  constexpr int M = Bz * S;
  constexpr long NELEM = (long)M * D;
  constexpr long WELEM = (long)D * D;

  const float qscale = 0.08838834764831845f * LOG2E;
  dim3 gridG(D / 128, M / 128);

  const size_t need_full = (size_t)(6 * NELEM + 4 * WELEM) * 2;

  if (ws_size >= need_full) {
    unsigned short* Qp  = (unsigned short*)d_ws;
    unsigned short* Kp  = Qp + NELEM;
    unsigned short* Vt  = Kp + NELEM;
    unsigned short* Xq  = Vt + NELEM;
    unsigned short* Xk  = Xq + NELEM;
    unsigned short* Xv  = Xk + NELEM;
    unsigned short* Wqb = Xv + NELEM;
    unsigned short* Wkb = Wqb + WELEM;
    unsigned short* Wvb = Wkb + WELEM;
    unsigned short* Wob = Wvb + WELEM;
    unsigned short* Oa  = Xq;

    cvt7_k<<<dim3(4096, 7), 256, 0, stream>>>(
        query, key_, value, Wq, Wk, Wv, Wo,
        Xq, Xk, Xv, Wqb, Wkb, Wvb, Wob, (int)NELEM, (int)WELEM);

    gemmqkv_k<<<dim3(16, 16, 3), 512, 0, stream>>>(
        Xq, Xk, Xv, Wqb, Wkb, Wvb, bq, bk, bv, Qp, Kp, Vt, qscale);

    flash_attn_k<<<dim3(8, 32), 512, 0, stream>>>(Qp, Kp, Vt, Oa);

    gemmo_k<<<dim3(16, 16), 512, 0, stream>>>(Oa, Wob, bo, out);
  } else {
    unsigned short* Qp = (unsigned short*)d_ws;
    unsigned short* Kp = Qp + NELEM;
    unsigned short* Vt = Kp + NELEM;
    unsigned short* Oa = Vt + NELEM;

    gemm_bias_k<false, true, false><<<gridG, 256, 0, stream>>>(query, Wq, bq, Qp, M, D, D, qscale);
    gemm_bias_k<false, true, false><<<gridG, 256, 0, stream>>>(key_,  Wk, bk, Kp, M, D, D, 1.0f);
    gemm_bias_k<false, true, true ><<<gridG, 256, 0, stream>>>(value, Wv, bv, Vt, M, D, D, 1.0f);

    flash_attn_k<<<dim3(8, 32), 512, 0, stream>>>(Qp, Kp, Vt, Oa);

    gemm_bias_k<true, false, false><<<gridG, 256, 0, stream>>>(Oa, Wo, bo, out, M, D, D, 1.0f);
  }
}

// Round 9
// 408.808 us; speedup vs baseline: 1.0059x; 1.0059x over previous
//
#include <hip/hip_runtime.h>
#include <hip/hip_bf16.h>

// B=2, S=2048, D=2048, H=16, HD=128, causal MHA with 4 linear projections.
// one cvt launch (uniform grid, 3 activations + 4 weights) -> batched QKV GEMM
// (ks-split 2-phase, hoisted frag reads, counted vmcnt, XCD-clustered blocks,
// V transposed per head) -> flash attn (256-thr blocks, single-buffered K/V,
// 1024 one-q-tile blocks big-first => 3 blocks/CU latency cover, transposed
// scores, per-lane softmax rows, lane-partial l_i, XCD-grouped heads) ->
// out-proj GEMM (same schedule).

#define LOG2E 1.44269504088896340736f

typedef __attribute__((ext_vector_type(8))) short short8;    // 8 x bf16
typedef __attribute__((ext_vector_type(4))) short short4b;   // 4 x bf16
typedef __attribute__((ext_vector_type(4))) float floatx4;   // MFMA acc

__device__ __forceinline__ short f2bf(float f) {
  unsigned int u = __builtin_bit_cast(unsigned int, f);
  u += 0x7FFFu + ((u >> 16) & 1u);  // RNE
  return (short)(u >> 16);
}

__device__ __forceinline__ short8 cvt8(float4 f0, float4 f1) {
  return (short8){f2bf(f0.x), f2bf(f0.y), f2bf(f0.z), f2bf(f0.w),
                  f2bf(f1.x), f2bf(f1.y), f2bf(f1.z), f2bf(f1.w)};
}

__device__ __forceinline__ short4b pack4bf(float a, float b, float c, float d) {
  __hip_bfloat162 lo = __float22bfloat162_rn(float2{a, b});
  __hip_bfloat162 hi = __float22bfloat162_rn(float2{c, d});
  short4b r;
  r[0] = __builtin_bit_cast(short, lo.x); r[1] = __builtin_bit_cast(short, lo.y);
  r[2] = __builtin_bit_cast(short, hi.x); r[3] = __builtin_bit_cast(short, hi.y);
  return r;
}

__device__ __forceinline__ void gl_lds16(const void* g, void* l) {
  __builtin_amdgcn_global_load_lds(
      (const __attribute__((address_space(1))) unsigned int*)g,
      (__attribute__((address_space(3))) unsigned int*)l, 16, 0, 0);
}

// ---------------- fp32 -> bf16 conversion, 7 tensors, uniform grid ----------
__global__ __launch_bounds__(256) void cvt7_k(
    const float* __restrict__ s0, const float* __restrict__ s1,
    const float* __restrict__ s2, const float* __restrict__ s3,
    const float* __restrict__ s4, const float* __restrict__ s5,
    const float* __restrict__ s6,
    unsigned short* __restrict__ d0, unsigned short* __restrict__ d1,
    unsigned short* __restrict__ d2, unsigned short* __restrict__ d3,
    unsigned short* __restrict__ d4, unsigned short* __restrict__ d5,
    unsigned short* __restrict__ d6, int nAct, int nW)
{
  const float* s; unsigned short* d; int n;
  switch (blockIdx.y) {
    case 0: s = s0; d = d0; n = nAct; break;
    case 1: s = s1; d = d1; n = nAct; break;
    case 2: s = s2; d = d2; n = nAct; break;
    case 3: s = s3; d = d3; n = nW; break;
    case 4: s = s4; d = d4; n = nW; break;
    case 5: s = s5; d = d5; n = nW; break;
    default: s = s6; d = d6; n = nW; break;
  }
  const long i = ((long)blockIdx.x * 256 + threadIdx.x) * 8;
  if (i >= n) return;
  float4 a = *(const float4*)(s + i);
  float4 b = *(const float4*)(s + i + 4);
  *(short8*)(d + i) = cvt8(a, b);
}

// ============ shared GEMM body (ks-split 2-phase, hoisted reads) =============
#define GEMM_CORE(A_, Bt_)                                                     \
  const unsigned short* gA[4]; int lAo[4];                                     \
  const unsigned short* gB[2]; int lBo[2];                                     \
  _Pragma("unroll")                                                            \
  for (int j = 0; j < 4; ++j) {                                                \
    const int pa = ((j >> 1) * 16 + wave * 2 + (j & 1)) * 64 + lane;           \
    const int r = pa >> 3, cp = pa & 7, cs = cp ^ (r & 7);                     \
    gA[j]  = A_ + (bm + r) * (long)K + cs * 8;                                 \
    lAo[j] = pa * 8;                                                           \
  }                                                                            \
  _Pragma("unroll")                                                            \
  for (int j = 0; j < 2; ++j) {                                                \
    const int pb = (wave * 2 + j) * 64 + lane;                                 \
    const int r = pb >> 3, cp = pb & 7, cs = cp ^ (r & 7);                     \
    gB[j]  = Bt_ + (bn + r) * (long)K + cs * 8;                                \
    lBo[j] = pb * 8;                                                           \
  }                                                                            \
  floatx4 acc[4][4];                                                           \
  _Pragma("unroll")                                                            \
  for (int i = 0; i < 4; ++i)                                                  \
    _Pragma("unroll")                                                          \
    for (int j = 0; j < 4; ++j) acc[i][j] = (floatx4){0.f, 0.f, 0.f, 0.f};     \
  const int NT = K >> 6;                                                       \
  _Pragma("unroll")                                                            \
  for (int j = 0; j < 4; ++j) gl_lds16(gA[j], &As[0][lAo[j]]);                 \
  _Pragma("unroll")                                                            \
  for (int j = 0; j < 2; ++j) gl_lds16(gB[j], &Bs[0][lBo[j]]);                 \
  if (NT > 1) {                                                                \
    _Pragma("unroll")                                                          \
    for (int j = 0; j < 4; ++j) gl_lds16(gA[j] + 64, &As[1][lAo[j]]);          \
    _Pragma("unroll")                                                          \
    for (int j = 0; j < 2; ++j) gl_lds16(gB[j] + 64, &Bs[1][lBo[j]]);          \
    asm volatile("s_waitcnt vmcnt(6)" ::: "memory");                           \
  } else {                                                                     \
    asm volatile("s_waitcnt vmcnt(0)" ::: "memory");                           \
  }                                                                            \
  __builtin_amdgcn_s_barrier();                                                \
  int cur3 = 0;                                                                \
  for (int t = 0; t < NT; ++t) {                                               \
    int nx2 = cur3 + 2; if (nx2 >= 3) nx2 -= 3;                                \
    const long kk2 = (long)(t + 2) * 64;                                       \
    const bool st2 = (t + 2) < NT;                                             \
    const bool st1 = (t + 1) < NT;                                             \
    const unsigned short* Ab = As[cur3];                                       \
    const unsigned short* Bb = Bs[cur3];                                       \
    short8 af0[4], bf0[4], af1[4], bf1[4];                                     \
    _Pragma("unroll")                                                          \
    for (int mt = 0; mt < 4; ++mt)                                             \
      af0[mt] = *(const short8*)&Ab[(wm * 64 + mt * 16 + l16) * 64 +           \
                                    ((quad ^ lx7) * 8)];                       \
    _Pragma("unroll")                                                          \
    for (int nt = 0; nt < 4; ++nt)                                             \
      bf0[nt] = *(const short8*)&Bb[(wn * 64 + nt * 16 + l16) * 64 +           \
                                    ((quad ^ lx7) * 8)];                       \
    _Pragma("unroll")                                                          \
    for (int mt = 0; mt < 4; ++mt)                                             \
      af1[mt] = *(const short8*)&Ab[(wm * 64 + mt * 16 + l16) * 64 +           \
                                    (((4 + quad) ^ lx7) * 8)];                 \
    _Pragma("unroll")                                                          \
    for (int nt = 0; nt < 4; ++nt)                                             \
      bf1[nt] = *(const short8*)&Bb[(wn * 64 + nt * 16 + l16) * 64 +           \
                                    (((4 + quad) ^ lx7) * 8)];                 \
    if (st2) { gl_lds16(gA[0] + kk2, &As[nx2][lAo[0]]);                        \
               gl_lds16(gA[1] + kk2, &As[nx2][lAo[1]]);                        \
               gl_lds16(gA[2] + kk2, &As[nx2][lAo[2]]); }                      \
    __builtin_amdgcn_s_barrier();                                              \
    __builtin_amdgcn_s_setprio(1);                                             \
    _Pragma("unroll")                                                          \
    for (int nt = 0; nt < 4; ++nt)                                             \
      _Pragma("unroll")                                                        \
      for (int mt = 0; mt < 4; ++mt)                                           \
        acc[mt][nt] = __builtin_amdgcn_mfma_f32_16x16x32_bf16(                 \
            af0[mt], bf0[nt], acc[mt][nt], 0, 0, 0);                           \
    __builtin_amdgcn_s_setprio(0);                                             \
    __builtin_amdgcn_s_barrier();                                              \
    if (st2) { gl_lds16(gA[3] + kk2, &As[nx2][lAo[3]]);                        \
               gl_lds16(gB[0] + kk2, &Bs[nx2][lBo[0]]);                        \
               gl_lds16(gB[1] + kk2, &Bs[nx2][lBo[1]]); }                      \
    __builtin_amdgcn_s_setprio(1);                                             \
    _Pragma("unroll")                                                          \
    for (int nt = 0; nt < 4; ++nt)                                             \
      _Pragma("unroll")                                                        \
      for (int mt = 0; mt < 4; ++mt)                                           \
        acc[mt][nt] = __builtin_amdgcn_mfma_f32_16x16x32_bf16(                 \
            af1[mt], bf1[nt], acc[mt][nt], 0, 0, 0);                           \
    __builtin_amdgcn_s_setprio(0);                                             \
    if (st1) {                                                                 \
      if (st2) asm volatile("s_waitcnt vmcnt(6)" ::: "memory");                \
      else     asm volatile("s_waitcnt vmcnt(0)" ::: "memory");                \
    }                                                                          \
    __builtin_amdgcn_s_barrier();                                              \
    cur3 = cur3 + 1 >= 3 ? 0 : cur3 + 1;                                       \
  }

// ---------------- batched QKV GEMM (z = 0:Q, 1:K, 2:V-transposed) -----------
__global__ __launch_bounds__(512, 1) void gemmqkv_k(
    const unsigned short* __restrict__ Aq, const unsigned short* __restrict__ Ak,
    const unsigned short* __restrict__ Av,
    const unsigned short* __restrict__ Bq, const unsigned short* __restrict__ Bk,
    const unsigned short* __restrict__ Bv,
    const float* __restrict__ biq, const float* __restrict__ bik,
    const float* __restrict__ biv,
    unsigned short* __restrict__ Cq, unsigned short* __restrict__ Ck,
    unsigned short* __restrict__ Cv, float qalpha)
{
  constexpr int K = 2048, N = 2048;
  __shared__ __align__(16) unsigned short As[3][256 * 64];
  __shared__ __align__(16) unsigned short Bs[3][128 * 64];

  const int tid  = threadIdx.x;
  const int lane = tid & 63;
  const int wave = tid >> 6;
  const int quad = lane >> 4;
  const int l16  = lane & 15;
  const int lx7  = l16 & 7;
  const int wm   = wave >> 1, wn = wave & 1;

  const unsigned short* A; const unsigned short* Bt; const float* bias;
  unsigned short* C; float alpha = 1.0f; bool vt = false;
  if (blockIdx.z == 0)      { A = Aq; Bt = Bq; bias = biq; C = Cq; alpha = qalpha; }
  else if (blockIdx.z == 1) { A = Ak; Bt = Bk; bias = bik; C = Ck; }
  else                      { A = Av; Bt = Bv; bias = biv; C = Cv; vt = true; }

  // XCD-cluster swizzle (bijective on 16x16): XCD = lin%8 gets 8x4 rectangle.
  const int lin  = (int)(blockIdx.y * 16 + blockIdx.x);
  const int xcd  = lin & 7;
  const int slot = lin >> 3;
  const int bx = (xcd & 1) * 8 + (slot & 7);
  const int by = (xcd >> 1) * 4 + (slot >> 3);
  const long bm = (long)by * 256;
  const long bn = (long)bx * 128;

  GEMM_CORE(A, Bt)

  if (vt) {
    __syncthreads();
    unsigned short* Ct = &As[0][0];  // [128 col][264] transpose staging
#pragma unroll
    for (int nt = 0; nt < 4; ++nt) {
      const int col_l = wn * 64 + nt * 16 + l16;
      const float bval = bias[bn + col_l];
#pragma unroll
      for (int mt = 0; mt < 4; ++mt) {
        const int row_l = wm * 64 + mt * 16 + quad * 4;
#pragma unroll
        for (int rg = 0; rg < 4; ++rg)
          Ct[col_l * 264 + row_l + rg] = (unsigned short)f2bf((acc[mt][nt][rg] + bval) * alpha);
      }
    }
    __syncthreads();
    const int b  = (int)(bm >> 11);
    const int s0 = (int)(bm & 2047);
    const int d   = tid >> 2;   // 0..127
    const int seg = tid & 3;
    unsigned short* dst = C +
        ((long)(b * 16 + bx) * 128 + d) * 2048 + s0 + seg * 64;
    const unsigned short* src = &Ct[d * 264 + seg * 64];
#pragma unroll
    for (int c = 0; c < 8; ++c)
      *(uint4*)(dst + c * 8) = *(const uint4*)(src + c * 8);
  } else {
#pragma unroll
    for (int nt = 0; nt < 4; ++nt) {
      const long col = bn + wn * 64 + nt * 16 + l16;
      const float bval = bias[col];
#pragma unroll
      for (int mt = 0; mt < 4; ++mt) {
#pragma unroll
        for (int rg = 0; rg < 4; ++rg) {
          const long row = bm + wm * 64 + mt * 16 + quad * 4 + rg;
          C[row * (long)N + col] = (unsigned short)f2bf((acc[mt][nt][rg] + bval) * alpha);
        }
      }
    }
  }
}

// ---------------- single GEMM (out-proj): bf16 A -> fp32 out ----------------
__global__ __launch_bounds__(512, 1) void gemmo_k(
    const unsigned short* __restrict__ A, const unsigned short* __restrict__ Bt,
    const float* __restrict__ bias, float* __restrict__ C)
{
  constexpr int K = 2048, N = 2048;
  __shared__ __align__(16) unsigned short As[3][256 * 64];
  __shared__ __align__(16) unsigned short Bs[3][128 * 64];

  const int tid  = threadIdx.x;
  const int lane = tid & 63;
  const int wave = tid >> 6;
  const int quad = lane >> 4;
  const int l16  = lane & 15;
  const int lx7  = l16 & 7;
  const int wm   = wave >> 1, wn = wave & 1;

  const int lin  = (int)(blockIdx.y * 16 + blockIdx.x);
  const int xcd  = lin & 7;
  const int slot = lin >> 3;
  const int bx = (xcd & 1) * 8 + (slot & 7);
  const int by = (xcd >> 1) * 4 + (slot >> 3);
  const long bm = (long)by * 256;
  const long bn = (long)bx * 128;

  GEMM_CORE(A, Bt)

#pragma unroll
  for (int nt = 0; nt < 4; ++nt) {
    const long col = bn + wn * 64 + nt * 16 + l16;
    const float bval = bias[col];
#pragma unroll
    for (int mt = 0; mt < 4; ++mt) {
#pragma unroll
      for (int rg = 0; rg < 4; ++rg) {
        const long row = bm + wm * 64 + mt * 16 + quad * 4 + rg;
        C[row * (long)N + col] = (acc[mt][nt][rg] + bval);
      }
    }
  }
}

// ---------------- fallback GEMM (fp32 operands) -----------------------------
template<bool A_BF16, bool OUT_BF16, bool VT_OUT>
__global__ __launch_bounds__(256, 2) void gemm_bias_k(
    const void* __restrict__ Aptr, const float* __restrict__ Bt,
    const float* __restrict__ bias, void* __restrict__ Cptr,
    int M, int N, int K, float alpha)
{
  __shared__ __align__(16) unsigned short smem[128 * 136];
  unsigned short* As = smem;
  unsigned short* Bs = smem + 128 * 40;

  const int tid  = threadIdx.x;
  const int lane = tid & 63;
  const int wave = tid >> 6;
  const int quad = lane >> 4;
  const int l16  = lane & 15;
  const int wr   = wave >> 1, wc = wave & 1;
  const long bm  = (long)blockIdx.y * 128;
  const long bn  = (long)blockIdx.x * 128;

  floatx4 acc[4][4];
#pragma unroll
  for (int i = 0; i < 4; ++i)
#pragma unroll
    for (int j = 0; j < 4; ++j) acc[i][j] = (floatx4){0.f, 0.f, 0.f, 0.f};

  const int srow = tid >> 2;
  const int cc   = tid & 3;

  for (int k0 = 0; k0 < K; k0 += 32) {
    __syncthreads();
#pragma unroll
    for (int r = 0; r < 2; ++r) {
      const int row = srow + r * 64;
      short8 av, bv;
      if (A_BF16) {
        av = *(const short8*)((const unsigned short*)Aptr + (bm + row) * (long)K + k0 + cc * 8);
      } else {
        const float* ap = (const float*)Aptr + (bm + row) * (long)K + k0 + cc * 8;
        av = cvt8(*(const float4*)ap, *(const float4*)(ap + 4));
      }
      {
        const float* bp = Bt + (bn + row) * (long)K + k0 + cc * 8;
        bv = cvt8(*(const float4*)bp, *(const float4*)(bp + 4));
      }
      *(short8*)&As[row * 40 + cc * 8] = av;
      *(short8*)&Bs[row * 40 + cc * 8] = bv;
    }
    __syncthreads();

    short8 af[4], bf[4];
#pragma unroll
    for (int t = 0; t < 4; ++t) {
      af[t] = *(const short8*)&As[(wr * 64 + t * 16 + l16) * 40 + quad * 8];
      bf[t] = *(const short8*)&Bs[(wc * 64 + t * 16 + l16) * 40 + quad * 8];
    }
#pragma unroll
    for (int mt = 0; mt < 4; ++mt)
#pragma unroll
      for (int nt = 0; nt < 4; ++nt)
        acc[mt][nt] = __builtin_amdgcn_mfma_f32_16x16x32_bf16(af[mt], bf[nt], acc[mt][nt], 0, 0, 0);
  }

  if (VT_OUT) {
    __syncthreads();
    unsigned short* Ct = smem;
#pragma unroll
    for (int nt = 0; nt < 4; ++nt) {
      const long col = bn + wc * 64 + nt * 16 + l16;
      const float bval = bias[col];
      const int col_l = wc * 64 + nt * 16 + l16;
#pragma unroll
      for (int mt = 0; mt < 4; ++mt) {
        const int row_l = wr * 64 + mt * 16 + quad * 4;
#pragma unroll
        for (int rg = 0; rg < 4; ++rg)
          Ct[col_l * 136 + row_l + rg] = (unsigned short)f2bf((acc[mt][nt][rg] + bval) * alpha);
      }
    }
    __syncthreads();
    const int b  = (int)(bm >> 11);
    const int s0 = (int)(bm & 2047);
    const int r    = tid >> 1;
    const int half = tid & 1;
    unsigned short* dst = (unsigned short*)Cptr +
        ((long)(b * 16 + blockIdx.x) * 128 + r) * 2048 + s0 + half * 64;
    const unsigned short* src = &Ct[r * 136 + half * 64];
#pragma unroll
    for (int c = 0; c < 8; ++c)
      *(uint4*)(dst + c * 8) = *(const uint4*)(src + c * 8);
  } else {
#pragma unroll
    for (int nt = 0; nt < 4; ++nt) {
      const long col = bn + wc * 64 + nt * 16 + l16;
      const float bval = bias[col];
#pragma unroll
      for (int mt = 0; mt < 4; ++mt) {
#pragma unroll
        for (int rg = 0; rg < 4; ++rg) {
          const long row = bm + wr * 64 + mt * 16 + quad * 4 + rg;
          const float v = (acc[mt][nt][rg] + bval) * alpha;
          if (OUT_BF16) ((unsigned short*)Cptr)[row * (long)N + col] = (unsigned short)f2bf(v);
          else          ((float*)Cptr)[row * (long)N + col] = v;
        }
      }
    }
  }
}

// ---------------- flash attention: 3-blocks/CU latency cover ----------------
// Q,K,O: bf16 [B,S,H,HD] (Q pre-scaled by SCALE*LOG2E). Vt: bf16 [B*H][HD][S].
// 256 thr = 4 waves; ONE 64-row q-tile per block; grid (8,128) = 1024 blocks.
// Single-buffered K/V (LDS 41.9KB -> 3 blocks/CU resident: the serial
// stage->vmcnt->barrier->QK->softmax->PV chain of one block hides under the
// other two). Big q-tiles dispatched first (qt = 31 - (by>>2)) so the causal
// triangle imbalance smooths across the 3-deep residency. bx = XCD owns heads
// 4bx..4bx+3 (4MB K+V = its L2). Per-iter math identical to the verified
// 2-block version -> bitwise-identical output.
__global__ __launch_bounds__(256, 3) void flash_attn_k(
    const unsigned short* __restrict__ Q,
    const unsigned short* __restrict__ Kp,
    const unsigned short* __restrict__ Vt,
    unsigned short* __restrict__ O)
{
  constexpr int S = 2048, D = 2048, HD = 128;
  constexpr int PS = 72;  // Ps stride (shorts)

  __shared__ __align__(16) unsigned short Ks[64 * 128];    // [k][d], swizzled
  __shared__ __align__(16) unsigned short Vst[128 * 64];   // [d][k], swizzled
  __shared__ __align__(16) unsigned short Ps[64 * PS];     // [q_local][k]

  const int tid  = threadIdx.x;
  const int lane = tid & 63;
  const int w    = tid >> 6;
  const int quad = lane >> 4;
  const int l16  = lane & 15;
  const int lx7  = l16 & 7;

  // grid (8,128): bx = XCD (lin%8), owns heads 4bx..4bx+3.
  const int bx = blockIdx.x;             // 0..7
  const int by = blockIdx.y;             // 0..127
  const int qt = 31 - (by >> 2);         // big tiles dispatched first
  const int bh = bx * 4 + (by & 3);

  const long headoff = (long)(bh >> 4) * S * D + (long)(bh & 15) * HD;
  const long vtoff   = (long)bh * HD * S;

  // staging plan (per-tile: add kbase)
  const unsigned short* gK[4]; unsigned short* lK[4];
  const unsigned short* gV[4]; unsigned short* lV[4];
#pragma unroll
  for (int i = 0; i < 4; ++i) {
    const int p = (w * 4 + i) * 64 + lane;          // 0..1023
    { const int r = p >> 4, cp = p & 15, c = cp ^ (r & 7);
      gK[i] = Kp + headoff + (long)r * D + c * 8;  lK[i] = &Ks[p * 8]; }
    { const int r = p >> 3, cp = p & 7, c = cp ^ (r & 7);
      gV[i] = Vt + vtoff + (long)r * S + c * 8;    lV[i] = &Vst[p * 8]; }
  }

  const int qbase = qt * 64;
  const int qrow  = qbase + w * 16 + l16;   // this lane's q row
  const int qloc  = w * 16 + l16;

  // Q fragments (B-operand layout: n = l16 = own row, k-chunks of 32)
  short8 aq[4];
  {
    const unsigned short* qp = Q + headoff + (long)qrow * D;
#pragma unroll
    for (int ks = 0; ks < 4; ++ks)
      aq[ks] = *(const short8*)(qp + ks * 32 + quad * 8);
  }

  floatx4 o_acc[8];
#pragma unroll
  for (int t = 0; t < 8; ++t) o_acc[t] = (floatx4){0.f, 0.f, 0.f, 0.f};
  float m_i = -INFINITY;   // row-uniform (updates use row-reduced max)
  float l_p = 0.f;         // per-lane partial of l_i

  for (int kt = 0; kt <= qt; ++kt) {
    const int kbase = kt * 64;
#pragma unroll
    for (int i = 0; i < 4; ++i) gl_lds16(gK[i] + (long)kbase * D, lK[i]);
#pragma unroll
    for (int i = 0; i < 4; ++i) gl_lds16(gV[i] + kbase, lV[i]);
    asm volatile("s_waitcnt vmcnt(0)" ::: "memory");
    __builtin_amdgcn_s_barrier();   // B1: tile kt visible to all waves

    // S^T tile: sc[nt] D-layout: k_local = nt*16 + quad*4 + rg, q-col = l16
    floatx4 sc[4];
#pragma unroll
    for (int nt = 0; nt < 4; ++nt) sc[nt] = (floatx4){0.f, 0.f, 0.f, 0.f};
    __builtin_amdgcn_s_setprio(1);
#pragma unroll
    for (int nt = 0; nt < 4; ++nt) {
      const int krow = nt * 16 + l16;
#pragma unroll
      for (int ks = 0; ks < 4; ++ks) {
        const int cp = (ks * 4 + quad) ^ lx7;
        short8 kf = *(const short8*)&Ks[krow * 128 + cp * 8];
        sc[nt] = __builtin_amdgcn_mfma_f32_16x16x32_bf16(kf, aq[ks], sc[nt], 0, 0, 0);
      }
    }
    __builtin_amdgcn_s_setprio(0);

    float sv[4][4];
    float lmax = -INFINITY;   // lane-local max over its 16 k-values
    if (kt == qt) {  // diagonal tile only: causal mask
      const int kg0 = kbase + quad * 4;
#pragma unroll
      for (int nt = 0; nt < 4; ++nt)
#pragma unroll
        for (int rg = 0; rg < 4; ++rg) {
          float v = sc[nt][rg];
          if (kg0 + nt * 16 + rg > qrow) v = -INFINITY;
          sv[nt][rg] = v;
          lmax = fmaxf(lmax, v);
        }
    } else {
#pragma unroll
      for (int nt = 0; nt < 4; ++nt)
#pragma unroll
        for (int rg = 0; rg < 4; ++rg) {
          sv[nt][rg] = sc[nt][rg];
          lmax = fmaxf(lmax, sc[nt][rg]);
        }
    }

    // defer-max: lane-local check == row check (m_i row-uniform). Shuffles
    // only on the rare rescale path.
    float al = 1.0f;
    if (__any(lmax > m_i + 8.0f)) {
      float rmax = fmaxf(lmax, __shfl_xor(lmax, 16));
      rmax = fmaxf(rmax, __shfl_xor(rmax, 32));
      const float mn = fmaxf(m_i, rmax);
      al = exp2f(m_i - mn);
      m_i = mn;
#pragma unroll
      for (int t = 0; t < 8; ++t)
#pragma unroll
        for (int rg = 0; rg < 4; ++rg) o_acc[t][rg] *= al;
    }

    float rsum = 0.f;
#pragma unroll
    for (int nt = 0; nt < 4; ++nt) {
      float p0 = exp2f(sv[nt][0] - m_i), p1 = exp2f(sv[nt][1] - m_i);
      float p2 = exp2f(sv[nt][2] - m_i), p3 = exp2f(sv[nt][3] - m_i);
      rsum += (p0 + p1) + (p2 + p3);
      *(short4b*)&Ps[qloc * PS + nt * 16 + quad * 4] = pack4bf(p0, p1, p2, p3);
    }
    l_p = l_p * al + rsum;   // lane-partial; al row-uniform -> sums correctly

    // P fragments (wave-private region of Ps: same-wave write->read, in-order DS)
    short8 pf[2];
#pragma unroll
    for (int ks = 0; ks < 2; ++ks)
      pf[ks] = *(const short8*)&Ps[qloc * PS + ks * 32 + quad * 8];

    // O^T += Vt_tile . P^T
    __builtin_amdgcn_s_setprio(1);
#pragma unroll
    for (int t = 0; t < 8; ++t) {
      const int drow = t * 16 + l16;
#pragma unroll
      for (int ks = 0; ks < 2; ++ks) {
        const int cp = (ks * 4 + quad) ^ lx7;
        short8 vf = *(const short8*)&Vst[drow * 64 + cp * 8];
        o_acc[t] = __builtin_amdgcn_mfma_f32_16x16x32_bf16(vf, pf[ks], o_acc[t], 0, 0, 0);
      }
    }
    __builtin_amdgcn_s_setprio(0);
    __builtin_amdgcn_s_barrier();   // B2: all waves done reading buffers
  }

  // epilogue: reduce lane-partial l, then lane holds O[qrow][d=t*16+quad*4+rg]
  float l_i = l_p + __shfl_xor(l_p, 16);
  l_i += __shfl_xor(l_i, 32);
  const float rl = 1.0f / l_i;
  unsigned short* op = O + headoff + (long)qrow * D;
#pragma unroll
  for (int t = 0; t < 8; ++t) {
    *(short4b*)(op + t * 16 + quad * 4) =
        pack4bf(o_acc[t][0] * rl, o_acc[t][1] * rl, o_acc[t][2] * rl, o_acc[t][3] * rl);
  }
}

extern "C" void kernel_launch(void* const* d_in, const int* in_sizes, int n_in,
                              void* d_out, int out_size, void* d_ws, size_t ws_size,
                              hipStream_t stream) {
  const float* query = (const float*)d_in[0];
  const float* key_  = (const float*)d_in[1];
  const float* value = (const float*)d_in[2];
  const float* Wq = (const float*)d_in[3];
  const float* bq = (const float*)d_in[4];
  const float* Wk = (const float*)d_in[5];
  const float* bk = (const float*)d_in[6];
  const float* Wv = (const float*)d_in[7];
  const float* bv = (const float*)d_in[8];
  const float* Wo = (const float*)d_in[9];
  const float* bo = (const float*)d_in[10];
  float* out = (float*)d_out;

  constexpr int Bz = 2, S = 2048, D = 2048;
  constexpr int M = Bz * S;
  constexpr long NELEM = (long)M * D;
  constexpr long WELEM = (long)D * D;

  const float qscale = 0.08838834764831845f * LOG2E;
  dim3 gridG(D / 128, M / 128);

  const size_t need_full = (size_t)(6 * NELEM + 4 * WELEM) * 2;

  if (ws_size >= need_full) {
    unsigned short* Qp  = (unsigned short*)d_ws;
    unsigned short* Kp  = Qp + NELEM;
    unsigned short* Vt  = Kp + NELEM;
    unsigned short* Xq  = Vt + NELEM;
    unsigned short* Xk  = Xq + NELEM;
    unsigned short* Xv  = Xk + NELEM;
    unsigned short* Wqb = Xv + NELEM;
    unsigned short* Wkb = Wqb + WELEM;
    unsigned short* Wvb = Wkb + WELEM;
    unsigned short* Wob = Wvb + WELEM;
    unsigned short* Oa  = Xq;

    cvt7_k<<<dim3(4096, 7), 256, 0, stream>>>(
        query, key_, value, Wq, Wk, Wv, Wo,
        Xq, Xk, Xv, Wqb, Wkb, Wvb, Wob, (int)NELEM, (int)WELEM);

    gemmqkv_k<<<dim3(16, 16, 3), 512, 0, stream>>>(
        Xq, Xk, Xv, Wqb, Wkb, Wvb, bq, bk, bv, Qp, Kp, Vt, qscale);

    flash_attn_k<<<dim3(8, 128), 256, 0, stream>>>(Qp, Kp, Vt, Oa);

    gemmo_k<<<dim3(16, 16), 512, 0, stream>>>(Oa, Wob, bo, out);
  } else {
    unsigned short* Qp = (unsigned short*)d_ws;
    unsigned short* Kp = Qp + NELEM;
    unsigned short* Vt = Kp + NELEM;
    unsigned short* Oa = Vt + NELEM;

    gemm_bias_k<false, true, false><<<gridG, 256, 0, stream>>>(query, Wq, bq, Qp, M, D, D, qscale);
    gemm_bias_k<false, true, false><<<gridG, 256, 0, stream>>>(key_,  Wk, bk, Kp, M, D, D, 1.0f);
    gemm_bias_k<false, true, true ><<<gridG, 256, 0, stream>>>(value, Wv, bv, Vt, M, D, D, 1.0f);

    flash_attn_k<<<dim3(8, 128), 256, 0, stream>>>(Qp, Kp, Vt, Oa);

    gemm_bias_k<true, false, false><<<gridG, 256, 0, stream>>>(Oa, Wo, bo, out, M, D, D, 1.0f);
  }
}